// Round 15
// baseline (605.117 us; speedup 1.0000x reference)
//
#include <hip/hip_runtime.h>
#include <hip/hip_bf16.h>

#define DD   64      // feature dim
#define NL   5       // layers
#define NT   37      // classes
#define LD   (NL*DD) // 320
#define PB   16      // CSR row padding quantum = gather batch depth
#define NBMAX 512    // max dst-buckets (256 nodes each) for the bucketed CSR build

typedef __attribute__((ext_vector_type(8))) short short8;   // 8 bf16 = 4 VGPRs
typedef __attribute__((ext_vector_type(4))) float f32x4;    // MFMA accumulator
typedef __attribute__((ext_vector_type(4))) int   i32x4;
typedef __attribute__((ext_vector_type(2))) int   i32x2;

static __device__ __forceinline__ int padq(int d) { return (d + PB - 1) & ~(PB - 1); }
static __device__ __forceinline__ short bf16_bits(float f) {
    __hip_bfloat16 h = __float2bfloat16(f);
    return __builtin_bit_cast(short, h);
}
static __device__ __forceinline__ float bf2f(short s) {
    return __int_as_float(((int)(unsigned short)s) << 16);
}

// ---------------------------------------------------------------------------
// Fused init: x -> bf16 h, W_mlp -> Wt, W_edge/b_edge -> zero-padded webt
// [64 feats][32 k] (k<7 = W_edge, k==7 = b_edge for the record-1.0 bias trick),
// bcnt zeroing. do_deg=1 adds the legacy atomic degree histogram (fallback).
__global__ void init_kernel(const float* __restrict__ x, __hip_bfloat16* __restrict__ hb,
                            size_t n1, const float* __restrict__ W,
                            __hip_bfloat16* __restrict__ Wt, int n2,
                            const float* __restrict__ W_edge, const float* __restrict__ b_edge,
                            __hip_bfloat16* __restrict__ webt, int* __restrict__ bcnt,
                            const int* __restrict__ dst, int* __restrict__ deg, int E,
                            int do_deg) {
    size_t i = (size_t)blockIdx.x * blockDim.x + threadIdx.x;
    if (i < n1) {
        hb[i] = __float2bfloat16(x[i]);
    } else if (i < n1 + (size_t)n2) {
        size_t id = i - n1;
        int l = (int)(id / (DD * DD));
        int r = (int)(id % (DD * DD));
        int c = r / DD, k = r % DD;
        Wt[(size_t)l * DD * DD + c * DD + k] =
            __float2bfloat16(W[(size_t)l * DD * DD + k * DD + c]);
    } else if (i < n1 + (size_t)n2 + 2048) {
        int id = (int)(i - n1 - (size_t)n2);     // id = f*32 + k
        int f = id >> 5, k = id & 31;
        float v = (k < 7) ? W_edge[k * DD + f] : (k == 7 ? b_edge[f] : 0.f);
        webt[id] = __float2bfloat16(v);
    } else if (i < n1 + (size_t)n2 + 2048 + NBMAX) {
        bcnt[i - n1 - (size_t)n2 - 2048] = 0;
    } else if (do_deg) {
        size_t e = i - n1 - (size_t)n2 - 2048 - NBMAX;
        if (e < (size_t)E) atomicAdd(&deg[dst[e]], 1);
    }
}

// ---------------------------------------------------------------------------
// Bucketed CSR build. Bucket = dst >> 8 (256 nodes each).
// R24: bhist/pscat widened to 512 threads, 2048 edges/block (1:1 thread:bucket)
// — same occupancy transformation validated on place_kernel in R21 (5->10+
// waves/CU on a 611-block grid vs 306). bdeg walk strides blockDim.
__global__ void bhist_kernel(const int* __restrict__ dst, int* __restrict__ bcnt, int E) {
    __shared__ int h[NBMAX];
    int tid = threadIdx.x;            // 0..511
    h[tid] = 0;
    __syncthreads();
    int base = blockIdx.x * 2048;
#pragma unroll
    for (int j = 0; j < 4; ++j) {
        int e = base + j * 512 + tid;
        if (e < E) atomicAdd(&h[dst[e] >> 8], 1);
    }
    __syncthreads();
    int c = h[tid];
    if (c) atomicAdd(&bcnt[tid], c);
}

__global__ void bscan_kernel(const int* __restrict__ bcnt, int* __restrict__ boff,
                             int* __restrict__ bcur) {
    __shared__ int sm[256];
    int tid = threadIdx.x;
    int v0 = bcnt[2 * tid], v1 = bcnt[2 * tid + 1];
    int s = v0 + v1;
    sm[tid] = s;
    __syncthreads();
    for (int off = 1; off < 256; off <<= 1) {
        int t = (tid >= off) ? sm[tid - off] : 0;
        __syncthreads();
        sm[tid] += t;
        __syncthreads();
    }
    int p = sm[tid] - s;
    boff[2 * tid] = p;     bcur[2 * tid] = p;     p += v0;
    boff[2 * tid + 1] = p; bcur[2 * tid + 1] = p; p += v1;
    if (tid == 255) boff[512] = p;
}

__global__ void pscat_kernel(const int* __restrict__ dst, int* __restrict__ bcur,
                             i32x2* __restrict__ stage, int E) {
    __shared__ int h[NBMAX];
    __shared__ int runb[NBMAX];
    int tid = threadIdx.x;            // 0..511
    h[tid] = 0;
    __syncthreads();
    int base = blockIdx.x * 2048;
    int d[4];
#pragma unroll
    for (int j = 0; j < 4; ++j) {
        int e = base + j * 512 + tid;
        d[j] = (e < E) ? dst[e] : -1;
        if (d[j] >= 0) atomicAdd(&h[d[j] >> 8], 1);
    }
    __syncthreads();
    int c = h[tid];
    runb[tid] = c ? atomicAdd(&bcur[tid], c) : 0;
    __syncthreads();
    h[tid] = 0;
    __syncthreads();
#pragma unroll
    for (int j = 0; j < 4; ++j) {
        if (d[j] >= 0) {
            int b = d[j] >> 8;
            int r = atomicAdd(&h[b], 1);
            i32x2 pr; pr[0] = base + j * 512 + tid; pr[1] = d[j];
            stage[runb[b] + r] = pr;
        }
    }
}

__global__ void bdeg_kernel(const i32x2* __restrict__ stage, const int* __restrict__ boff,
                            int* __restrict__ deg, int n) {
    __shared__ int cnt[256];
    int tid = threadIdx.x;
    int b = blockIdx.x;
    if (tid < 256) cnt[tid] = 0;
    __syncthreads();
    int s = boff[b], e = boff[b + 1];
    for (int j = s + tid; j < e; j += blockDim.x)
        atomicAdd(&cnt[stage[j][1] & 255], 1);
    __syncthreads();
    int node = b * 256 + tid;
    if (tid < 256 && node < n) deg[node] = cnt[tid];
}

// R21-validated fine placement, 512 threads (heavy record loop strides
// blockDim; LDS cursors + pad-tail stay on tid<256).
template<bool PACKED>
__global__ void place_kernel(const i32x2* __restrict__ stage, const int* __restrict__ boff,
                             const int* __restrict__ rowptr, const int* __restrict__ src,
                             const float* __restrict__ ea,
                             short* __restrict__ eab, int* __restrict__ srcv,
                             int* __restrict__ col, int n) {
    __shared__ int cur[256];
    int tid = threadIdx.x;
    int b = blockIdx.x;
    int node = b * 256 + tid;
    if (tid < 256) cur[tid] = (node < n) ? rowptr[node] : 0;
    __syncthreads();
    int s = boff[b], e = boff[b + 1];
    for (int j = s + tid; j < e; j += blockDim.x) {
        i32x2 pr = stage[j];
        int eid = pr[0], d = pr[1];
        int slot = atomicAdd(&cur[d & 255], 1);
        srcv[slot] = src[eid];
        if (PACKED) {
            const float* a = ea + (size_t)eid * 7;
            short8 r;
#pragma unroll
            for (int k = 0; k < 7; ++k) r[k] = bf16_bits(a[k]);
            r[7] = (short)0x3F80;       // bf16(1.0) bias row
            *((i32x4*)(eab + (size_t)slot * 8)) = __builtin_bit_cast(i32x4, r);
        } else {
            col[slot] = eid;
        }
    }
    __syncthreads();
    if (tid < 256 && node < n) {
        int endp = rowptr[node + 1];
        for (int i = cur[tid]; i < endp; ++i) {
            srcv[i] = 0;
            if (PACKED) {
                i32x4 z = {0, 0, 0, 0};
                *((i32x4*)(eab + (size_t)i * 8)) = z;
            } else {
                col[i] = 0;
            }
        }
    }
}

// ---------------------------------------------------------------------------
// scans operate on PADDED degrees (rows padded to multiple of PB)
__global__ void chunksum_kernel(const int* __restrict__ deg, int* __restrict__ csum, int n) {
    __shared__ int sm[256];
    int tid = threadIdx.x;
    int base = blockIdx.x * 1024 + tid * 4;
    int s = 0;
#pragma unroll
    for (int j = 0; j < 4; ++j) s += (base + j < n) ? padq(deg[base + j]) : 0;
    sm[tid] = s;
    __syncthreads();
    for (int off = 128; off > 0; off >>= 1) {
        if (tid < off) sm[tid] += sm[tid + off];
        __syncthreads();
    }
    if (tid == 0) csum[blockIdx.x] = sm[0];
}

__global__ void scansums_kernel(int* __restrict__ csum, int nc, int* __restrict__ tot) {
    __shared__ int sm[256];
    int tid = threadIdx.x;
    int base = tid * 4;
    int v[4]; int s = 0;
#pragma unroll
    for (int j = 0; j < 4; ++j) { v[j] = (base + j < nc) ? csum[base + j] : 0; s += v[j]; }
    sm[tid] = s;
    __syncthreads();
    for (int off = 1; off < 256; off <<= 1) {
        int t = (tid >= off) ? sm[tid - off] : 0;
        __syncthreads();
        sm[tid] += t;
        __syncthreads();
    }
    int p = sm[tid] - s;
#pragma unroll
    for (int j = 0; j < 4; ++j) { if (base + j < nc) csum[base + j] = p; p += v[j]; }
    if (tid == 255) *tot = p;
}

__global__ void chunkscan_kernel(const int* __restrict__ deg, const int* __restrict__ csum,
                                 int* __restrict__ rowptr, int* __restrict__ cursor, int n) {
    __shared__ int sm[256];
    int tid = threadIdx.x;
    int base = blockIdx.x * 1024 + tid * 4;
    int v[4]; int s = 0;
#pragma unroll
    for (int j = 0; j < 4; ++j) { v[j] = (base + j < n) ? padq(deg[base + j]) : 0; s += v[j]; }
    sm[tid] = s;
    __syncthreads();
    for (int off = 1; off < 256; off <<= 1) {
        int t = (tid >= off) ? sm[tid - off] : 0;
        __syncthreads();
        sm[tid] += t;
        __syncthreads();
    }
    int p = sm[tid] - s + csum[blockIdx.x];
#pragma unroll
    for (int j = 0; j < 4; ++j) {
        if (base + j < n) { rowptr[base + j] = p; cursor[base + j] = p; }
        p += v[j];
    }
}

// ---------------------------------------------------------------------------
// FALLBACK path kernels (pre-R13): used only when the bucketed build can't run.
__global__ void fillpos_kernel(const int* __restrict__ dst, int* __restrict__ cursor,
                               int* __restrict__ col, int E) {
    int e = blockIdx.x * blockDim.x + threadIdx.x;
    if (e >= E) return;
    int p = atomicAdd(&cursor[dst[e]], 1);
    col[p] = e;
}

__global__ void padmark_kernel(const int* __restrict__ deg, const int* __restrict__ rowptr,
                               int* __restrict__ col, int n) {
    int v = blockIdx.x * blockDim.x + threadIdx.x;
    if (v >= n) return;
    int s = rowptr[v] + deg[v];
    int e = rowptr[v + 1];
    for (int i = s; i < e; ++i) col[i] = -1;
}

template<bool PACKED>
__global__ void gfill_kernel(const int* __restrict__ col, const int* __restrict__ src,
                             const float* __restrict__ ea, const int* __restrict__ rowptrN,
                             short* __restrict__ eab, int* __restrict__ srcv,
                             int* __restrict__ colw) {
    int slot = blockIdx.x * blockDim.x + threadIdx.x;
    if (slot >= *rowptrN) return;
    int e = col[slot];
    int s = 0;
    short8 r;
#pragma unroll
    for (int k = 0; k < 8; ++k) r[k] = 0;
    if (e >= 0) {
        s = src[e];
        if (PACKED) {
            const float* a = ea + (size_t)e * 7;
#pragma unroll
            for (int k = 0; k < 7; ++k) r[k] = bf16_bits(a[k]);
            r[7] = (short)0x3F80;
        }
    } else if (!PACKED) {
        colw[slot] = 0;
    }
    __builtin_nontemporal_store(s, &srcv[slot]);
    if (PACKED) {
        i32x4 ri = __builtin_bit_cast(i32x4, r);
        __builtin_nontemporal_store(ri, (i32x4*)(eab + (size_t)slot * 8));
    }
}

template<bool PACKED>
__global__ void fill_kernel(const int* __restrict__ dst, const int* __restrict__ src,
                            const float* __restrict__ ea, int* __restrict__ cursor,
                            short* __restrict__ eab, int* __restrict__ col,
                            int* __restrict__ srcv, int E) {
    int e = blockIdx.x * blockDim.x + threadIdx.x;
    if (e >= E) return;
    int p = atomicAdd(&cursor[dst[e]], 1);
    int s = src[e];
    __builtin_nontemporal_store(s, &srcv[p]);
    if (PACKED) {
        const float* a = ea + (size_t)e * 7;
        short8 r;
#pragma unroll
        for (int k = 0; k < 7; ++k) r[k] = bf16_bits(a[k]);
        r[7] = (short)0x3F80;
        i32x4 ri = __builtin_bit_cast(i32x4, r);
        __builtin_nontemporal_store(ri, (i32x4*)(eab + (size_t)p * 8));
    } else {
        __builtin_nontemporal_store(e, &col[p]);
    }
}

__global__ void padfill_kernel(const int* __restrict__ deg, const int* __restrict__ rowptr,
                               int* __restrict__ srcv, int* __restrict__ col,
                               int has_col, int n) {
    int v = blockIdx.x * blockDim.x + threadIdx.x;
    if (v >= n) return;
    int s = rowptr[v] + deg[v];
    int e = rowptr[v + 1];
    for (int i = s; i < e; ++i) {
        srcv[i] = 0;
        if (has_col) col[i] = 0;
    }
}

// ---------------------------------------------------------------------------
// Scalar per-row aggregation (validated R10 loop) — slow path (deg>16) and
// fallback tiers. Ends with per-lane=feat accumulator (compatible with MFMA path).
template<bool PACKED>
static __device__ __forceinline__ float row_partial(
    const __hip_bfloat16* __restrict__ hb_in, const short* __restrict__ eab,
    const int* __restrict__ col, const float* __restrict__ ea,
    const int* __restrict__ srcv, int beg, int dv, int lane,
    const float* __restrict__ we, float be) {
    float acc = 0.f;
    int end = beg + dv;
    for (int p = beg; p < end; p += PB) {
        int mm = end - p;        // wave-uniform
        int S[PB];
#pragma unroll
        for (int j = 0; j < PB; ++j) S[j] = srcv[p + j];
        __hip_bfloat16 hv[PB];
#pragma unroll
        for (int j = 0; j < PB; ++j) hv[j] = hb_in[(size_t)S[j] * DD + lane];
        float ev[PB][7];
        if (PACKED) {
            short8 eb[PB];
#pragma unroll
            for (int j = 0; j < PB; ++j)
                eb[j] = *((const short8*)(eab + (size_t)(p + j) * 8));
#pragma unroll
            for (int j = 0; j < PB; ++j)
#pragma unroll
                for (int k = 0; k < 7; ++k) ev[j][k] = bf2f(eb[j][k]);
        } else {
            int EJ[PB];
#pragma unroll
            for (int j = 0; j < PB; ++j) EJ[j] = col[p + j];
#pragma unroll
            for (int j = 0; j < PB; ++j) {
                const float* a = ea + (size_t)EJ[j] * 7;
#pragma unroll
                for (int k = 0; k < 7; ++k) ev[j][k] = a[k];
            }
        }
#pragma unroll
        for (int j = 0; j < PB; ++j) {
            if (j < mm) {
                float emb = be + ev[j][0] * we[0] + ev[j][1] * we[1] + ev[j][2] * we[2]
                               + ev[j][3] * we[3] + ev[j][4] * we[4] + ev[j][5] * we[5]
                               + ev[j][6] * we[6];
                float tv = __bfloat162float(hv[j]) + emb;
                acc += (tv > 0.f) ? tv : 0.f;
            }
        }
    }
    return acc;
}

template<bool PACKED>
static __device__ __forceinline__ void agg_pair(
    const __hip_bfloat16* __restrict__ hb_in, const short* __restrict__ eab,
    const int* __restrict__ col, const float* __restrict__ ea,
    const int* __restrict__ srcv, int beg0, int d0, int beg1, int d1, bool has1,
    int lane, const float* __restrict__ we, float be, float& acc0, float& acc1) {
    acc0 = row_partial<PACKED>(hb_in, eab, col, ea, srcv, beg0, d0, lane, we, be);
    acc1 = 0.f;
    if (has1)
        acc1 = row_partial<PACKED>(hb_in, eab, col, ea, srcv, beg1, d1, lane, we, be);
}

// ---------------------------------------------------------------------------
// R21-validated FUSED agg+MLP (best measured config): R16 structure + hoisted
// per-node rowptr/deg loads; launch_bounds (256,4) is the cache-friendly
// operating point (R20: 8 waves/EU tripled traffic; R22: pair-batching raised
// VGPR 32->48, occupancy 57->39%, net regression).
__global__ __launch_bounds__(256, 4)
void aggmlp_kernel(const __hip_bfloat16* __restrict__ hb_in,
                   const short* __restrict__ eab, const int* __restrict__ srcv,
                   const int* __restrict__ rowptr, const int* __restrict__ deg,
                   const float* __restrict__ W_edge, const float* __restrict__ b_edge,
                   const __hip_bfloat16* __restrict__ webt,
                   const float* __restrict__ eps, int layer,
                   const __hip_bfloat16* __restrict__ Wt, const float* __restrict__ bmlp,
                   __hip_bfloat16* __restrict__ hb_out, int n) {
    __shared__ __align__(16) short uls[16][72];   // stride 144B: aligned b128, <=2-way banks
    const unsigned short* hbu = (const unsigned short*)hb_in;
    int tid = threadIdx.x;
    int lane = tid & 63;
    int wv = __builtin_amdgcn_readfirstlane(tid >> 6);
    int base = blockIdx.x * 16;
    int colx = lane & 15;
    int q = lane >> 4;

    // scalar-path constants
    float we[7];
#pragma unroll
    for (int k = 0; k < 7; ++k) we[k] = W_edge[k * DD + lane];
    float be = b_edge[lane];
    float epsv = 1.f + eps[layer];

    // MFMA-path B tiles (persistent, 16 VGPRs)
    short8 wb[4];
#pragma unroll
    for (int t = 0; t < 4; ++t)
        wb[t] = *((const short8*)(webt + (size_t)(t * 16 + colx) * 32 + q * 8));

    // Hoisted per-node row metadata (independent scalar loads, issued early)
    int pv_[4], dv_[4];
#pragma unroll
    for (int nd = 0; nd < 4; ++nd) {
        int v = base + wv * 4 + nd;
        pv_[nd] = (v < n) ? rowptr[v] : 0;
        dv_[nd] = (v < n) ? deg[v] : 0;
    }

#pragma unroll
    for (int nd = 0; nd < 4; ++nd) {
        int v = base + wv * 4 + nd;            // wave-uniform
        if (v < n) {
            int p = pv_[nd];
            int d = dv_[nd];
            float nodeacc;
            if (d >= 1 && d <= PB) {
                // ---- MFMA fast path: one padded 16-slot row
                short8 a = {0, 0, 0, 0, 0, 0, 0, 0};
                if (q == 0)
                    a = *((const short8*)(eab + (size_t)(p + colx) * 8));
                int sr0 = srcv[p + 4 * q + 0];
                int sr1 = srcv[p + 4 * q + 1];
                int sr2 = srcv[p + 4 * q + 2];
                int sr3 = srcv[p + 4 * q + 3];
                f32x4 z = {0.f, 0.f, 0.f, 0.f};
                f32x4 emb[4];
#pragma unroll
                for (int t = 0; t < 4; ++t)
                    emb[t] = __builtin_amdgcn_mfma_f32_16x16x32_bf16(a, wb[t], z, 0, 0, 0);
                unsigned short hv[4][4];
#pragma unroll
                for (int t = 0; t < 4; ++t) {
                    hv[0][t] = hbu[(size_t)sr0 * DD + t * 16 + colx];
                    hv[1][t] = hbu[(size_t)sr1 * DD + t * 16 + colx];
                    hv[2][t] = hbu[(size_t)sr2 * DD + t * 16 + colx];
                    hv[3][t] = hbu[(size_t)sr3 * DD + t * 16 + colx];
                }
                float ts[4];
#pragma unroll
                for (int t = 0; t < 4; ++t) {
                    float s = 0.f;
#pragma unroll
                    for (int r = 0; r < 4; ++r) {
                        float tv = __int_as_float((int)hv[r][t] << 16) + emb[t][r];
                        float rv = ((4 * q + r) < d) ? ((tv > 0.f) ? tv : 0.f) : 0.f;
                        s += rv;
                    }
                    s += __shfl_xor(s, 16, 64);
                    s += __shfl_xor(s, 32, 64);
                    ts[t] = s;
                }
                nodeacc = (q == 0) ? ts[0] : (q == 1) ? ts[1] : (q == 2) ? ts[2] : ts[3];
            } else {
                // ---- scalar path: deg==0 (no-op) or deg>16 (chunked loop)
                nodeacc = row_partial<true>(hb_in, eab, nullptr, nullptr, srcv,
                                            p, d, lane, we, be);
            }
            float self = __int_as_float((int)hbu[(size_t)v * DD + lane] << 16);
            uls[wv * 4 + nd][lane] = bf16_bits(epsv * self + nodeacc);
        }
    }
    __syncthreads();

    if (wv == 0) {
        short8 wf[4][2];
#pragma unroll
        for (int t = 0; t < 4; ++t)
#pragma unroll
            for (int s = 0; s < 2; ++s)
                wf[t][s] = *((const short8*)(Wt + (size_t)(t * 16 + colx) * DD + s * 32 + q * 8));
        float bias[4];
#pragma unroll
        for (int t = 0; t < 4; ++t) bias[t] = bmlp[t * 16 + colx];

        short8 a0 = *((const short8*)&uls[colx][q * 8]);
        short8 a1 = *((const short8*)&uls[colx][32 + q * 8]);

        f32x4 acc[4] = {{0.f, 0.f, 0.f, 0.f}, {0.f, 0.f, 0.f, 0.f},
                        {0.f, 0.f, 0.f, 0.f}, {0.f, 0.f, 0.f, 0.f}};
#pragma unroll
        for (int t = 0; t < 4; ++t) {
            acc[t] = __builtin_amdgcn_mfma_f32_16x16x32_bf16(a0, wf[t][0], acc[t], 0, 0, 0);
            acc[t] = __builtin_amdgcn_mfma_f32_16x16x32_bf16(a1, wf[t][1], acc[t], 0, 0, 0);
        }
#pragma unroll
        for (int r = 0; r < 4; ++r) {
            int v = base + q * 4 + r;
            if (v < n) {
#pragma unroll
                for (int t = 0; t < 4; ++t) {
                    float val = acc[t][r] + bias[t];
                    val = (val > 0.f) ? val : 0.f;
                    hb_out[(size_t)v * DD + t * 16 + colx] = __float2bfloat16(val);
                }
            }
        }
    }
}

// ---------------------------------------------------------------------------
// Standalone aggregation — fallback tiers.
template<bool PACKED>
__global__ __launch_bounds__(256, 4)
void agg_kernel(const __hip_bfloat16* __restrict__ hb_in,
                const short* __restrict__ eab,
                const int* __restrict__ col, const int* __restrict__ srcv,
                const float* __restrict__ ea,
                const int* __restrict__ rowptr, const int* __restrict__ deg,
                const float* __restrict__ W_edge, const float* __restrict__ b_edge,
                const float* __restrict__ eps, int layer,
                __hip_bfloat16* __restrict__ u, int n) {
    int lane = threadIdx.x & 63;
    int wid = __builtin_amdgcn_readfirstlane(blockIdx.x * 4 + (threadIdx.x >> 6));
    int v0 = wid * 2;
    if (v0 >= n) return;

    float we[7];
#pragma unroll
    for (int k = 0; k < 7; ++k) we[k] = W_edge[k * DD + lane];
    float be = b_edge[lane];
    float epsv = 1.f + eps[layer];

    int beg0 = rowptr[v0];
    int d0   = deg[v0];
    bool has1 = (v0 + 1) < n;
    int beg1 = has1 ? rowptr[v0 + 1] : 0;
    int d1   = has1 ? deg[v0 + 1] : 0;

    float acc0, acc1;
    agg_pair<PACKED>(hb_in, eab, col, ea, srcv, beg0, d0, beg1, d1, has1,
                     lane, we, be, acc0, acc1);

    float self0 = __bfloat162float(hb_in[(size_t)v0 * DD + lane]);
    u[(size_t)v0 * DD + lane] = __float2bfloat16(epsv * self0 + acc0);
    if (has1) {
        float self1 = __bfloat162float(hb_in[(size_t)(v0 + 1) * DD + lane]);
        u[(size_t)(v0 + 1) * DD + lane] = __float2bfloat16(epsv * self1 + acc1);
    }
}

// ---------------------------------------------------------------------------
// Standalone MFMA MLP — fallback tiers.
__global__ __launch_bounds__(256, 4)
void mlp_mfma_kernel(const __hip_bfloat16* __restrict__ u,
                     const __hip_bfloat16* __restrict__ Wt,
                     const float* __restrict__ bmlp,
                     __hip_bfloat16* __restrict__ hb_out, int n) {
    int lane = threadIdx.x & 63;
    int wid  = threadIdx.x >> 6;
    int colx = lane & 15;
    int quad = lane >> 4;
    int v0 = __builtin_amdgcn_readfirstlane((blockIdx.x * 4 + wid) * 16);
    if (v0 >= n) return;

    short8 wf[4][2];
#pragma unroll
    for (int t = 0; t < 4; ++t)
#pragma unroll
        for (int s = 0; s < 2; ++s)
            wf[t][s] = *((const short8*)(Wt + (size_t)(t * 16 + colx) * DD + s * 32 + quad * 8));
    float bias[4];
#pragma unroll
    for (int t = 0; t < 4; ++t) bias[t] = bmlp[t * 16 + colx];

    int vr = v0 + colx;
    int vrc = (vr < n) ? vr : (n - 1);
    const __hip_bfloat16* up = u + (size_t)vrc * DD;
    short8 a0 = *((const short8*)(up + quad * 8));
    short8 a1 = *((const short8*)(up + 32 + quad * 8));

    f32x4 acc[4] = {{0.f, 0.f, 0.f, 0.f}, {0.f, 0.f, 0.f, 0.f},
                    {0.f, 0.f, 0.f, 0.f}, {0.f, 0.f, 0.f, 0.f}};
#pragma unroll
    for (int t = 0; t < 4; ++t) {
        acc[t] = __builtin_amdgcn_mfma_f32_16x16x32_bf16(a0, wf[t][0], acc[t], 0, 0, 0);
        acc[t] = __builtin_amdgcn_mfma_f32_16x16x32_bf16(a1, wf[t][1], acc[t], 0, 0, 0);
    }

#pragma unroll
    for (int r = 0; r < 4; ++r) {
        int v = v0 + quad * 4 + r;
        if (v < n) {
#pragma unroll
            for (int t = 0; t < 4; ++t) {
                float val = acc[t][r] + bias[t];
                val = (val > 0.f) ? val : 0.f;
                hb_out[(size_t)v * DD + t * 16 + colx] = __float2bfloat16(val);
            }
        }
    }
}

// ---------------------------------------------------------------------------
// Pool partials: one block per (graph, layer). Zero atomics.
__global__ void pool_part_kernel(const __hip_bfloat16* __restrict__ htabs, size_t lstride,
                                 const int* __restrict__ batch,
                                 float* __restrict__ g_sum, int n, int G) {
    __shared__ float part[4][DD];
    __shared__ int bnd[2];
    int g = blockIdx.x / NL;
    int q = blockIdx.x % NL;
    int tid = threadIdx.x;
    if (tid < 2) {
        int target = g + tid;
        int lo = 0, hi = n;
        while (lo < hi) { int mid = (lo + hi) >> 1; if (batch[mid] < target) lo = mid + 1; else hi = mid; }
        bnd[tid] = lo;
    }
    __syncthreads();
    int lb = bnd[0], ub = bnd[1];
    int w = tid >> 6, f = tid & 63;
    const __hip_bfloat16* T = htabs + (size_t)q * lstride;
    float s = 0.f;
    for (int v = lb + w; v < ub; v += 4)
        s += __bfloat162float(T[(size_t)v * DD + f]);
    part[w][f] = s;
    __syncthreads();
    if (tid < DD) {
        float tot = part[0][f] + part[1][f] + part[2][f] + part[3][f];
        float c = (float)(ub - lb);
        if (c < 1.f) c = 1.f;
        g_sum[(size_t)g * LD + q * DD + f] = tot / c;
    }
}

__global__ void readout_mean_kernel(const float* __restrict__ g_mean,
                                    const float* __restrict__ W_pred,
                                    const float* __restrict__ b_pred,
                                    float* __restrict__ out, int G) {
    int id = blockIdx.x * blockDim.x + threadIdx.x;
    if (id >= G * NT) return;
    int g = id / NT, t = id % NT;
    float acc = b_pred[t];
    const float* gs = g_mean + (size_t)g * LD;
    for (int k = 0; k < LD; ++k) acc += gs[k] * W_pred[k * NT + t];
    out[id] = acc;
}

// ---------------------------------------------------------------------------
// Tier-2 fallback pool (run accumulation) + readout
__global__ void pool_kernel(const __hip_bfloat16* __restrict__ h, const int* __restrict__ batch,
                            float* __restrict__ g_sum, int layer, int n) {
    int wave = (blockIdx.x * blockDim.x + threadIdx.x) >> 6;
    int l = threadIdx.x & 63;
    int v0 = wave * 64;
    if (v0 >= n) return;
    int vend = min(v0 + 64, n);
    int cur = batch[v0];
    float acc = 0.f;
    for (int v = v0; v < vend; ++v) {
        int bv = batch[v];
        if (bv != cur) {
            atomicAdd(&g_sum[(size_t)cur * LD + layer * DD + l], acc);
            acc = 0.f;
            cur = bv;
        }
        acc += __bfloat162float(h[(size_t)v * DD + l]);
    }
    atomicAdd(&g_sum[(size_t)cur * LD + layer * DD + l], acc);
}

__global__ void graph_cnt_kernel(const int* __restrict__ batch, int* __restrict__ cnt,
                                 int n, int G) {
    int g = blockIdx.x * blockDim.x + threadIdx.x;
    if (g >= G) return;
    int lo = 0, hi = n;
    while (lo < hi) { int mid = (lo + hi) >> 1; if (batch[mid] < g) lo = mid + 1; else hi = mid; }
    int lb0 = lo;
    lo = lb0; hi = n;
    while (lo < hi) { int mid = (lo + hi) >> 1; if (batch[mid] < g + 1) lo = mid + 1; else hi = mid; }
    cnt[g] = lo - lb0;
}

__global__ void readout_kernel(const float* __restrict__ g_sum, const int* __restrict__ cnt,
                               const float* __restrict__ W_pred, const float* __restrict__ b_pred,
                               float* __restrict__ out, int G) {
    int id = blockIdx.x * blockDim.x + threadIdx.x;
    if (id >= G * NT) return;
    int g = id / NT, t = id % NT;
    float c = (float)cnt[g];
    if (c < 1.f) c = 1.f;
    float inv = 1.f / c;
    float acc = b_pred[t];
    const float* gs = g_sum + (size_t)g * LD;
    for (int k = 0; k < LD; ++k) acc += gs[k] * inv * W_pred[k * NT + t];
    out[id] = acc;
}

// ---------------------------------------------------------------------------
extern "C" void kernel_launch(void* const* d_in, const int* in_sizes, int n_in,
                              void* d_out, int out_size, void* d_ws, size_t ws_size,
                              hipStream_t stream) {
    const float* x       = (const float*)d_in[0];
    const int*   eidx    = (const int*)d_in[1];
    const float* ea      = (const float*)d_in[2];
    const int*   batch   = (const int*)d_in[3];
    const float* W_edge  = (const float*)d_in[4];
    const float* b_edge  = (const float*)d_in[5];
    const float* eps     = (const float*)d_in[6];
    const float* W_mlp   = (const float*)d_in[7];
    const float* b_mlp   = (const float*)d_in[8];
    const float* W_pred  = (const float*)d_in[9];
    const float* b_pred  = (const float*)d_in[10];
    float* out = (float*)d_out;

    const int N = in_sizes[3];          // 100000
    const int E = in_sizes[2] / 7;      // 1250000
    const int G = out_size / NT;        // 128
    const int* src = eidx;              // edge_index[0]
    const int* dst = eidx + E;          // edge_index[1]
    const int NC = (N + 1023) / 1024;
    const int NB = (N + 255) >> 8;      // dst-buckets (256 nodes each)
    const size_t SLOTS = (size_t)E + (size_t)(PB - 1) * N;   // padded-slot capacity

    const size_t S_h = (size_t)N * DD * 2;   // one bf16 table
    const size_t small = (size_t)N * 4 + (size_t)(N + 4) * 4 + (size_t)N * 4 + 4096
                       + 8192 + 4096                          // bucket arrays + webt
                       + (size_t)NL * DD * DD * 2             // Wt
                       + (size_t)G * LD * 4 + (((size_t)G * 4 + 15) & ~(size_t)15);
    const size_t needA = 7 * S_h + small + SLOTS * 20;  // bf16 records + srcv
    const size_t needB = 7 * S_h + small + SLOTS * 8;   // col + srcv
    const int tier = (ws_size >= needA) ? 0 : (ws_size >= needB) ? 1 : 2;
    const int nTab = (tier <= 1) ? 6 : 2;

    char* w = (char*)d_ws;
    __hip_bfloat16* hbt = (__hip_bfloat16*)w;  w += (size_t)nTab * S_h;
    __hip_bfloat16* u   = (__hip_bfloat16*)w;  w += S_h;
    __hip_bfloat16* Wt  = (__hip_bfloat16*)w;  w += (size_t)NL * DD * DD * 2;
    __hip_bfloat16* webt = (__hip_bfloat16*)w; w += 4096;    // [64][32] bf16
    int*   deg    = (int*)w;                   w += (size_t)N * 4;
    int*   rowptr = (int*)w;                   w += (size_t)(N + 4) * 4;
    int*   cursor = (int*)w;                   w += (size_t)N * 4;
    int*   csum   = (int*)w;                   w += 4096;
    int*   bcnt   = (int*)w;                   w += 2048;   // NBMAX ints
    int*   boff   = (int*)w;                   w += 2064;   // NBMAX+1 ints
    int*   bcur   = (int*)w;                   w += 2048;   // NBMAX ints
    float* g_sum  = (float*)w;                 w += (size_t)G * LD * 4;
    int*   cnt    = (int*)w;                   w += ((size_t)G * 4 + 15) & ~(size_t)15;
    short* eab = nullptr; int* col = nullptr; int* srcv = nullptr;
    if (tier == 0) {
        eab  = (short*)w;  w += SLOTS * 16;    // 16-B aligned
        srcv = (int*)w;
    } else {
        col  = (int*)w;    w += SLOTS * 4;
        srcv = (int*)w;
    }
    const bool packed = (tier == 0);

    // Bucketed CSR build requires: buckets fit LDS tables, pair staging fits u.
    const bool newcsr = (NB <= NBMAX) && ((size_t)E * 8 <= S_h);
    i32x2* stage = (i32x2*)u;                  // dead until first agg

    if (tier == 2) hipMemsetAsync(g_sum, 0, (size_t)G * LD * 4, stream);

    // Fused init: bf16 convert + W transpose + webt + bcnt zero (+ legacy deg)
    {
        size_t n1 = (size_t)N * DD;
        size_t tot = n1 + (size_t)(NL * DD * DD) + 2048 + NBMAX + (newcsr ? 0 : (size_t)E);
        if (!newcsr) hipMemsetAsync(deg, 0, (size_t)N * 4, stream);
        init_kernel<<<(unsigned)((tot + 255) / 256), 256, 0, stream>>>(
            x, hbt, n1, W_mlp, Wt, NL * DD * DD, W_edge, b_edge, webt, bcnt,
            dst, deg, E, newcsr ? 0 : 1);
    }

    if (newcsr) {
        unsigned eb2 = (unsigned)((E + 2047) / 2048);
        bhist_kernel<<<eb2, 512, 0, stream>>>(dst, bcnt, E);
        bscan_kernel<<<1, 256, 0, stream>>>(bcnt, boff, bcur);
        pscat_kernel<<<eb2, 512, 0, stream>>>(dst, bcur, stage, E);
        bdeg_kernel<<<NB, 512, 0, stream>>>(stage, boff, deg, N);
        chunksum_kernel<<<NC, 256, 0, stream>>>(deg, csum, N);
        scansums_kernel<<<1, 256, 0, stream>>>(csum, NC, rowptr + N);
        chunkscan_kernel<<<NC, 256, 0, stream>>>(deg, csum, rowptr, cursor, N);
        if (packed)
            place_kernel<true><<<NB, 512, 0, stream>>>(stage, boff, rowptr, src, ea,
                                                       eab, srcv, col, N);
        else
            place_kernel<false><<<NB, 512, 0, stream>>>(stage, boff, rowptr, src, ea,
                                                        eab, srcv, col, N);
    } else {
        chunksum_kernel<<<NC, 256, 0, stream>>>(deg, csum, N);
        scansums_kernel<<<1, 256, 0, stream>>>(csum, NC, rowptr + N);
        chunkscan_kernel<<<NC, 256, 0, stream>>>(deg, csum, rowptr, cursor, N);
        int* colbuf = nullptr;
        if (tier == 0) {
            if (SLOTS * 4 <= S_h) colbuf = (int*)u;
        } else {
            colbuf = col;
        }
        if (colbuf) {
            fillpos_kernel<<<(E + 255) / 256, 256, 0, stream>>>(dst, cursor, colbuf, E);
            padmark_kernel<<<(N + 255) / 256, 256, 0, stream>>>(deg, rowptr, colbuf, N);
            unsigned gblocks = (unsigned)((SLOTS + 255) / 256);
            if (packed)
                gfill_kernel<true><<<gblocks, 256, 0, stream>>>(colbuf, src, ea, rowptr + N,
                                                                eab, srcv, colbuf);
            else
                gfill_kernel<false><<<gblocks, 256, 0, stream>>>(colbuf, src, ea, rowptr + N,
                                                                 eab, srcv, colbuf);
        } else {
            if (packed)
                fill_kernel<true><<<(E + 255) / 256, 256, 0, stream>>>(dst, src, ea, cursor,
                                                                       eab, col, srcv, E);
            else
                fill_kernel<false><<<(E + 255) / 256, 256, 0, stream>>>(dst, src, ea, cursor,
                                                                        eab, col, srcv, E);
            padfill_kernel<<<(N + 255) / 256, 256, 0, stream>>>(deg, rowptr, srcv,
                                                                col ? col : srcv,
                                                                col ? 1 : 0, N);
        }
    }

    const bool useFused = newcsr && packed;
    int fusedBlocks = (N + 15) / 16;
    int aggBlocks = (N + 7) / 8;
    int mlpBlocks = (N + 63) / 64;
    for (int i = 0; i < NL; ++i) {
        __hip_bfloat16* hin  = (tier <= 1) ? (hbt + (size_t)i * N * DD)
                                           : (hbt + (size_t)(i & 1) * N * DD);
        __hip_bfloat16* hout = (tier <= 1) ? (hbt + (size_t)(i + 1) * N * DD)
                                           : (hbt + (size_t)((i + 1) & 1) * N * DD);
        if (useFused) {
            aggmlp_kernel<<<fusedBlocks, 256, 0, stream>>>(
                hin, eab, srcv, rowptr, deg, W_edge, b_edge, webt, eps, i,
                Wt + (size_t)i * DD * DD, b_mlp + (size_t)i * DD, hout, N);
        } else {
            if (packed)
                agg_kernel<true><<<aggBlocks, 256, 0, stream>>>(
                    hin, eab, col, srcv, ea, rowptr, deg, W_edge, b_edge, eps, i, u, N);
            else
                agg_kernel<false><<<aggBlocks, 256, 0, stream>>>(
                    hin, eab, col, srcv, ea, rowptr, deg, W_edge, b_edge, eps, i, u, N);
            mlp_mfma_kernel<<<mlpBlocks, 256, 0, stream>>>(
                u, Wt + (size_t)i * DD * DD, b_mlp + (size_t)i * DD, hout, N);
        }
        if (tier == 2)
            pool_kernel<<<((N + 63) / 64 * 64 + 255) / 256, 256, 0, stream>>>(hout, batch,
                                                                              g_sum, i, N);
    }

    if (tier <= 1) {
        pool_part_kernel<<<G * NL, 256, 0, stream>>>(hbt + (size_t)N * DD, (size_t)N * DD,
                                                     batch, g_sum, N, G);
        readout_mean_kernel<<<(G * NT + 255) / 256, 256, 0, stream>>>(g_sum, W_pred, b_pred,
                                                                      out, G);
    } else {
        graph_cnt_kernel<<<1, 128, 0, stream>>>(batch, cnt, N, G);
        readout_kernel<<<(G * NT + 255) / 256, 256, 0, stream>>>(g_sum, cnt, W_pred, b_pred,
                                                                 out, G);
    }
}

// Round 16
// 568.770 us; speedup vs baseline: 1.0639x; 1.0639x over previous
//
#include <hip/hip_runtime.h>
#include <hip/hip_bf16.h>

#define DD   64      // feature dim
#define NL   5       // layers
#define NT   37      // classes
#define LD   (NL*DD) // 320
#define PB   16      // CSR row padding quantum = gather batch depth
#define NBMAX 512    // max dst-buckets (256 nodes each) for the bucketed CSR build

typedef __attribute__((ext_vector_type(8))) short short8;   // 8 bf16 = 4 VGPRs
typedef __attribute__((ext_vector_type(4))) float f32x4;    // MFMA accumulator
typedef __attribute__((ext_vector_type(4))) int   i32x4;
typedef __attribute__((ext_vector_type(2))) int   i32x2;

static __device__ __forceinline__ int padq(int d) { return (d + PB - 1) & ~(PB - 1); }
static __device__ __forceinline__ short bf16_bits(float f) {
    __hip_bfloat16 h = __float2bfloat16(f);
    return __builtin_bit_cast(short, h);
}
static __device__ __forceinline__ float bf2f(short s) {
    return __int_as_float(((int)(unsigned short)s) << 16);
}

// ---------------------------------------------------------------------------
// Fused init: x -> bf16 h, W_mlp -> Wt, W_edge/b_edge -> zero-padded webt
// [64 feats][32 k] (k<7 = W_edge, k==7 = b_edge for the record-1.0 bias trick),
// bcnt zeroing. do_deg=1 adds the legacy atomic degree histogram (fallback).
__global__ void init_kernel(const float* __restrict__ x, __hip_bfloat16* __restrict__ hb,
                            size_t n1, const float* __restrict__ W,
                            __hip_bfloat16* __restrict__ Wt, int n2,
                            const float* __restrict__ W_edge, const float* __restrict__ b_edge,
                            __hip_bfloat16* __restrict__ webt, int* __restrict__ bcnt,
                            const int* __restrict__ dst, int* __restrict__ deg, int E,
                            int do_deg) {
    size_t i = (size_t)blockIdx.x * blockDim.x + threadIdx.x;
    if (i < n1) {
        hb[i] = __float2bfloat16(x[i]);
    } else if (i < n1 + (size_t)n2) {
        size_t id = i - n1;
        int l = (int)(id / (DD * DD));
        int r = (int)(id % (DD * DD));
        int c = r / DD, k = r % DD;
        Wt[(size_t)l * DD * DD + c * DD + k] =
            __float2bfloat16(W[(size_t)l * DD * DD + k * DD + c]);
    } else if (i < n1 + (size_t)n2 + 2048) {
        int id = (int)(i - n1 - (size_t)n2);     // id = f*32 + k
        int f = id >> 5, k = id & 31;
        float v = (k < 7) ? W_edge[k * DD + f] : (k == 7 ? b_edge[f] : 0.f);
        webt[id] = __float2bfloat16(v);
    } else if (i < n1 + (size_t)n2 + 2048 + NBMAX) {
        bcnt[i - n1 - (size_t)n2 - 2048] = 0;
    } else if (do_deg) {
        size_t e = i - n1 - (size_t)n2 - 2048 - NBMAX;
        if (e < (size_t)E) atomicAdd(&deg[dst[e]], 1);
    }
}

// ---------------------------------------------------------------------------
// Bucketed CSR build (R13/R16-validated shapes; R24 widening was null).
__global__ void bhist_kernel(const int* __restrict__ dst, int* __restrict__ bcnt, int E) {
    __shared__ int h[NBMAX];
    int tid = threadIdx.x;
    h[tid] = 0; h[tid + 256] = 0;
    __syncthreads();
    int base = blockIdx.x * 4096;
#pragma unroll
    for (int j = 0; j < 16; ++j) {
        int e = base + j * 256 + tid;
        if (e < E) atomicAdd(&h[dst[e] >> 8], 1);
    }
    __syncthreads();
    int c0 = h[tid], c1 = h[tid + 256];
    if (c0) atomicAdd(&bcnt[tid], c0);
    if (c1) atomicAdd(&bcnt[tid + 256], c1);
}

__global__ void bscan_kernel(const int* __restrict__ bcnt, int* __restrict__ boff,
                             int* __restrict__ bcur) {
    __shared__ int sm[256];
    int tid = threadIdx.x;
    int v0 = bcnt[2 * tid], v1 = bcnt[2 * tid + 1];
    int s = v0 + v1;
    sm[tid] = s;
    __syncthreads();
    for (int off = 1; off < 256; off <<= 1) {
        int t = (tid >= off) ? sm[tid - off] : 0;
        __syncthreads();
        sm[tid] += t;
        __syncthreads();
    }
    int p = sm[tid] - s;
    boff[2 * tid] = p;     bcur[2 * tid] = p;     p += v0;
    boff[2 * tid + 1] = p; bcur[2 * tid + 1] = p; p += v1;
    if (tid == 255) boff[512] = p;
}

__global__ void pscat_kernel(const int* __restrict__ dst, int* __restrict__ bcur,
                             i32x2* __restrict__ stage, int E) {
    __shared__ int h[NBMAX];
    __shared__ int runb[NBMAX];
    int tid = threadIdx.x;
    h[tid] = 0; h[tid + 256] = 0;
    __syncthreads();
    int base = blockIdx.x * 4096;
    int d[16];
#pragma unroll
    for (int j = 0; j < 16; ++j) {
        int e = base + j * 256 + tid;
        d[j] = (e < E) ? dst[e] : -1;
        if (d[j] >= 0) atomicAdd(&h[d[j] >> 8], 1);
    }
    __syncthreads();
    int c0 = h[tid], c1 = h[tid + 256];
    runb[tid]       = c0 ? atomicAdd(&bcur[tid], c0) : 0;
    runb[tid + 256] = c1 ? atomicAdd(&bcur[tid + 256], c1) : 0;
    __syncthreads();
    h[tid] = 0; h[tid + 256] = 0;
    __syncthreads();
#pragma unroll
    for (int j = 0; j < 16; ++j) {
        if (d[j] >= 0) {
            int b = d[j] >> 8;
            int r = atomicAdd(&h[b], 1);
            i32x2 pr; pr[0] = base + j * 256 + tid; pr[1] = d[j];
            stage[runb[b] + r] = pr;
        }
    }
}

__global__ void bdeg_kernel(const i32x2* __restrict__ stage, const int* __restrict__ boff,
                            int* __restrict__ deg, int n) {
    __shared__ int cnt[256];
    int tid = threadIdx.x;
    int b = blockIdx.x;
    cnt[tid] = 0;
    __syncthreads();
    int s = boff[b], e = boff[b + 1];
    for (int j = s + tid; j < e; j += 256)
        atomicAdd(&cnt[stage[j][1] & 255], 1);
    __syncthreads();
    int node = b * 256 + tid;
    if (node < n) deg[node] = cnt[tid];
}

// R21-validated fine placement, 512 threads (heavy record loop strides
// blockDim; LDS cursors + pad-tail stay on tid<256).
template<bool PACKED>
__global__ void place_kernel(const i32x2* __restrict__ stage, const int* __restrict__ boff,
                             const int* __restrict__ rowptr, const int* __restrict__ src,
                             const float* __restrict__ ea,
                             short* __restrict__ eab, int* __restrict__ srcv,
                             int* __restrict__ col, int n) {
    __shared__ int cur[256];
    int tid = threadIdx.x;
    int b = blockIdx.x;
    int node = b * 256 + tid;
    if (tid < 256) cur[tid] = (node < n) ? rowptr[node] : 0;
    __syncthreads();
    int s = boff[b], e = boff[b + 1];
    for (int j = s + tid; j < e; j += blockDim.x) {
        i32x2 pr = stage[j];
        int eid = pr[0], d = pr[1];
        int slot = atomicAdd(&cur[d & 255], 1);
        srcv[slot] = src[eid];
        if (PACKED) {
            const float* a = ea + (size_t)eid * 7;
            short8 r;
#pragma unroll
            for (int k = 0; k < 7; ++k) r[k] = bf16_bits(a[k]);
            r[7] = (short)0x3F80;       // bf16(1.0) bias row
            *((i32x4*)(eab + (size_t)slot * 8)) = __builtin_bit_cast(i32x4, r);
        } else {
            col[slot] = eid;
        }
    }
    __syncthreads();
    if (tid < 256 && node < n) {
        int endp = rowptr[node + 1];
        for (int i = cur[tid]; i < endp; ++i) {
            srcv[i] = 0;
            if (PACKED) {
                i32x4 z = {0, 0, 0, 0};
                *((i32x4*)(eab + (size_t)i * 8)) = z;
            } else {
                col[i] = 0;
            }
        }
    }
}

// ---------------------------------------------------------------------------
// scans operate on PADDED degrees (rows padded to multiple of PB)
__global__ void chunksum_kernel(const int* __restrict__ deg, int* __restrict__ csum, int n) {
    __shared__ int sm[256];
    int tid = threadIdx.x;
    int base = blockIdx.x * 1024 + tid * 4;
    int s = 0;
#pragma unroll
    for (int j = 0; j < 4; ++j) s += (base + j < n) ? padq(deg[base + j]) : 0;
    sm[tid] = s;
    __syncthreads();
    for (int off = 128; off > 0; off >>= 1) {
        if (tid < off) sm[tid] += sm[tid + off];
        __syncthreads();
    }
    if (tid == 0) csum[blockIdx.x] = sm[0];
}

__global__ void scansums_kernel(int* __restrict__ csum, int nc, int* __restrict__ tot) {
    __shared__ int sm[256];
    int tid = threadIdx.x;
    int base = tid * 4;
    int v[4]; int s = 0;
#pragma unroll
    for (int j = 0; j < 4; ++j) { v[j] = (base + j < nc) ? csum[base + j] : 0; s += v[j]; }
    sm[tid] = s;
    __syncthreads();
    for (int off = 1; off < 256; off <<= 1) {
        int t = (tid >= off) ? sm[tid - off] : 0;
        __syncthreads();
        sm[tid] += t;
        __syncthreads();
    }
    int p = sm[tid] - s;
#pragma unroll
    for (int j = 0; j < 4; ++j) { if (base + j < nc) csum[base + j] = p; p += v[j]; }
    if (tid == 255) *tot = p;
}

__global__ void chunkscan_kernel(const int* __restrict__ deg, const int* __restrict__ csum,
                                 int* __restrict__ rowptr, int* __restrict__ cursor, int n) {
    __shared__ int sm[256];
    int tid = threadIdx.x;
    int base = blockIdx.x * 1024 + tid * 4;
    int v[4]; int s = 0;
#pragma unroll
    for (int j = 0; j < 4; ++j) { v[j] = (base + j < n) ? padq(deg[base + j]) : 0; s += v[j]; }
    sm[tid] = s;
    __syncthreads();
    for (int off = 1; off < 256; off <<= 1) {
        int t = (tid >= off) ? sm[tid - off] : 0;
        __syncthreads();
        sm[tid] += t;
        __syncthreads();
    }
    int p = sm[tid] - s + csum[blockIdx.x];
#pragma unroll
    for (int j = 0; j < 4; ++j) {
        if (base + j < n) { rowptr[base + j] = p; cursor[base + j] = p; }
        p += v[j];
    }
}

// ---------------------------------------------------------------------------
// FALLBACK path kernels (pre-R13): used only when the bucketed build can't run.
__global__ void fillpos_kernel(const int* __restrict__ dst, int* __restrict__ cursor,
                               int* __restrict__ col, int E) {
    int e = blockIdx.x * blockDim.x + threadIdx.x;
    if (e >= E) return;
    int p = atomicAdd(&cursor[dst[e]], 1);
    col[p] = e;
}

__global__ void padmark_kernel(const int* __restrict__ deg, const int* __restrict__ rowptr,
                               int* __restrict__ col, int n) {
    int v = blockIdx.x * blockDim.x + threadIdx.x;
    if (v >= n) return;
    int s = rowptr[v] + deg[v];
    int e = rowptr[v + 1];
    for (int i = s; i < e; ++i) col[i] = -1;
}

template<bool PACKED>
__global__ void gfill_kernel(const int* __restrict__ col, const int* __restrict__ src,
                             const float* __restrict__ ea, const int* __restrict__ rowptrN,
                             short* __restrict__ eab, int* __restrict__ srcv,
                             int* __restrict__ colw) {
    int slot = blockIdx.x * blockDim.x + threadIdx.x;
    if (slot >= *rowptrN) return;
    int e = col[slot];
    int s = 0;
    short8 r;
#pragma unroll
    for (int k = 0; k < 8; ++k) r[k] = 0;
    if (e >= 0) {
        s = src[e];
        if (PACKED) {
            const float* a = ea + (size_t)e * 7;
#pragma unroll
            for (int k = 0; k < 7; ++k) r[k] = bf16_bits(a[k]);
            r[7] = (short)0x3F80;
        }
    } else if (!PACKED) {
        colw[slot] = 0;
    }
    __builtin_nontemporal_store(s, &srcv[slot]);
    if (PACKED) {
        i32x4 ri = __builtin_bit_cast(i32x4, r);
        __builtin_nontemporal_store(ri, (i32x4*)(eab + (size_t)slot * 8));
    }
}

template<bool PACKED>
__global__ void fill_kernel(const int* __restrict__ dst, const int* __restrict__ src,
                            const float* __restrict__ ea, int* __restrict__ cursor,
                            short* __restrict__ eab, int* __restrict__ col,
                            int* __restrict__ srcv, int E) {
    int e = blockIdx.x * blockDim.x + threadIdx.x;
    if (e >= E) return;
    int p = atomicAdd(&cursor[dst[e]], 1);
    int s = src[e];
    __builtin_nontemporal_store(s, &srcv[p]);
    if (PACKED) {
        const float* a = ea + (size_t)e * 7;
        short8 r;
#pragma unroll
        for (int k = 0; k < 7; ++k) r[k] = bf16_bits(a[k]);
        r[7] = (short)0x3F80;
        i32x4 ri = __builtin_bit_cast(i32x4, r);
        __builtin_nontemporal_store(ri, (i32x4*)(eab + (size_t)p * 8));
    } else {
        __builtin_nontemporal_store(e, &col[p]);
    }
}

__global__ void padfill_kernel(const int* __restrict__ deg, const int* __restrict__ rowptr,
                               int* __restrict__ srcv, int* __restrict__ col,
                               int has_col, int n) {
    int v = blockIdx.x * blockDim.x + threadIdx.x;
    if (v >= n) return;
    int s = rowptr[v] + deg[v];
    int e = rowptr[v + 1];
    for (int i = s; i < e; ++i) {
        srcv[i] = 0;
        if (has_col) col[i] = 0;
    }
}

// ---------------------------------------------------------------------------
// Scalar per-row aggregation (validated R10 loop) — slow path (deg>16) and
// fallback tiers. Ends with per-lane=feat accumulator (compatible with MFMA path).
template<bool PACKED>
static __device__ __forceinline__ float row_partial(
    const __hip_bfloat16* __restrict__ hb_in, const short* __restrict__ eab,
    const int* __restrict__ col, const float* __restrict__ ea,
    const int* __restrict__ srcv, int beg, int dv, int lane,
    const float* __restrict__ we, float be) {
    float acc = 0.f;
    int end = beg + dv;
    for (int p = beg; p < end; p += PB) {
        int mm = end - p;        // wave-uniform
        int S[PB];
#pragma unroll
        for (int j = 0; j < PB; ++j) S[j] = srcv[p + j];
        __hip_bfloat16 hv[PB];
#pragma unroll
        for (int j = 0; j < PB; ++j) hv[j] = hb_in[(size_t)S[j] * DD + lane];
        float ev[PB][7];
        if (PACKED) {
            short8 eb[PB];
#pragma unroll
            for (int j = 0; j < PB; ++j)
                eb[j] = *((const short8*)(eab + (size_t)(p + j) * 8));
#pragma unroll
            for (int j = 0; j < PB; ++j)
#pragma unroll
                for (int k = 0; k < 7; ++k) ev[j][k] = bf2f(eb[j][k]);
        } else {
            int EJ[PB];
#pragma unroll
            for (int j = 0; j < PB; ++j) EJ[j] = col[p + j];
#pragma unroll
            for (int j = 0; j < PB; ++j) {
                const float* a = ea + (size_t)EJ[j] * 7;
#pragma unroll
                for (int k = 0; k < 7; ++k) ev[j][k] = a[k];
            }
        }
#pragma unroll
        for (int j = 0; j < PB; ++j) {
            if (j < mm) {
                float emb = be + ev[j][0] * we[0] + ev[j][1] * we[1] + ev[j][2] * we[2]
                               + ev[j][3] * we[3] + ev[j][4] * we[4] + ev[j][5] * we[5]
                               + ev[j][6] * we[6];
                float tv = __bfloat162float(hv[j]) + emb;
                acc += (tv > 0.f) ? tv : 0.f;
            }
        }
    }
    return acc;
}

template<bool PACKED>
static __device__ __forceinline__ void agg_pair(
    const __hip_bfloat16* __restrict__ hb_in, const short* __restrict__ eab,
    const int* __restrict__ col, const float* __restrict__ ea,
    const int* __restrict__ srcv, int beg0, int d0, int beg1, int d1, bool has1,
    int lane, const float* __restrict__ we, float be, float& acc0, float& acc1) {
    acc0 = row_partial<PACKED>(hb_in, eab, col, ea, srcv, beg0, d0, lane, we, be);
    acc1 = 0.f;
    if (has1)
        acc1 = row_partial<PACKED>(hb_in, eab, col, ea, srcv, beg1, d1, lane, we, be);
}

// ---------------------------------------------------------------------------
// R21-validated FUSED agg+MLP (best measured config): R16 structure + hoisted
// per-node rowptr/deg loads; launch_bounds (256,4) is the cache-friendly
// operating point (R20: 8 waves/EU tripled traffic; R22: pair-batching raised
// VGPR 32->48, occupancy 57->39%, net regression).
__global__ __launch_bounds__(256, 4)
void aggmlp_kernel(const __hip_bfloat16* __restrict__ hb_in,
                   const short* __restrict__ eab, const int* __restrict__ srcv,
                   const int* __restrict__ rowptr, const int* __restrict__ deg,
                   const float* __restrict__ W_edge, const float* __restrict__ b_edge,
                   const __hip_bfloat16* __restrict__ webt,
                   const float* __restrict__ eps, int layer,
                   const __hip_bfloat16* __restrict__ Wt, const float* __restrict__ bmlp,
                   __hip_bfloat16* __restrict__ hb_out, int n) {
    __shared__ __align__(16) short uls[16][72];   // stride 144B: aligned b128, <=2-way banks
    const unsigned short* hbu = (const unsigned short*)hb_in;
    int tid = threadIdx.x;
    int lane = tid & 63;
    int wv = __builtin_amdgcn_readfirstlane(tid >> 6);
    int base = blockIdx.x * 16;
    int colx = lane & 15;
    int q = lane >> 4;

    // scalar-path constants
    float we[7];
#pragma unroll
    for (int k = 0; k < 7; ++k) we[k] = W_edge[k * DD + lane];
    float be = b_edge[lane];
    float epsv = 1.f + eps[layer];

    // MFMA-path B tiles (persistent, 16 VGPRs)
    short8 wb[4];
#pragma unroll
    for (int t = 0; t < 4; ++t)
        wb[t] = *((const short8*)(webt + (size_t)(t * 16 + colx) * 32 + q * 8));

    // Hoisted per-node row metadata (independent scalar loads, issued early)
    int pv_[4], dv_[4];
#pragma unroll
    for (int nd = 0; nd < 4; ++nd) {
        int v = base + wv * 4 + nd;
        pv_[nd] = (v < n) ? rowptr[v] : 0;
        dv_[nd] = (v < n) ? deg[v] : 0;
    }

#pragma unroll
    for (int nd = 0; nd < 4; ++nd) {
        int v = base + wv * 4 + nd;            // wave-uniform
        if (v < n) {
            int p = pv_[nd];
            int d = dv_[nd];
            float nodeacc;
            if (d >= 1 && d <= PB) {
                // ---- MFMA fast path: one padded 16-slot row
                short8 a = {0, 0, 0, 0, 0, 0, 0, 0};
                if (q == 0)
                    a = *((const short8*)(eab + (size_t)(p + colx) * 8));
                int sr0 = srcv[p + 4 * q + 0];
                int sr1 = srcv[p + 4 * q + 1];
                int sr2 = srcv[p + 4 * q + 2];
                int sr3 = srcv[p + 4 * q + 3];
                f32x4 z = {0.f, 0.f, 0.f, 0.f};
                f32x4 emb[4];
#pragma unroll
                for (int t = 0; t < 4; ++t)
                    emb[t] = __builtin_amdgcn_mfma_f32_16x16x32_bf16(a, wb[t], z, 0, 0, 0);
                unsigned short hv[4][4];
#pragma unroll
                for (int t = 0; t < 4; ++t) {
                    hv[0][t] = hbu[(size_t)sr0 * DD + t * 16 + colx];
                    hv[1][t] = hbu[(size_t)sr1 * DD + t * 16 + colx];
                    hv[2][t] = hbu[(size_t)sr2 * DD + t * 16 + colx];
                    hv[3][t] = hbu[(size_t)sr3 * DD + t * 16 + colx];
                }
                float ts[4];
#pragma unroll
                for (int t = 0; t < 4; ++t) {
                    float s = 0.f;
#pragma unroll
                    for (int r = 0; r < 4; ++r) {
                        float tv = __int_as_float((int)hv[r][t] << 16) + emb[t][r];
                        float rv = ((4 * q + r) < d) ? ((tv > 0.f) ? tv : 0.f) : 0.f;
                        s += rv;
                    }
                    s += __shfl_xor(s, 16, 64);
                    s += __shfl_xor(s, 32, 64);
                    ts[t] = s;
                }
                nodeacc = (q == 0) ? ts[0] : (q == 1) ? ts[1] : (q == 2) ? ts[2] : ts[3];
            } else {
                // ---- scalar path: deg==0 (no-op) or deg>16 (chunked loop)
                nodeacc = row_partial<true>(hb_in, eab, nullptr, nullptr, srcv,
                                            p, d, lane, we, be);
            }
            float self = __int_as_float((int)hbu[(size_t)v * DD + lane] << 16);
            uls[wv * 4 + nd][lane] = bf16_bits(epsv * self + nodeacc);
        }
    }
    __syncthreads();

    if (wv == 0) {
        short8 wf[4][2];
#pragma unroll
        for (int t = 0; t < 4; ++t)
#pragma unroll
            for (int s = 0; s < 2; ++s)
                wf[t][s] = *((const short8*)(Wt + (size_t)(t * 16 + colx) * DD + s * 32 + q * 8));
        float bias[4];
#pragma unroll
        for (int t = 0; t < 4; ++t) bias[t] = bmlp[t * 16 + colx];

        short8 a0 = *((const short8*)&uls[colx][q * 8]);
        short8 a1 = *((const short8*)&uls[colx][32 + q * 8]);

        f32x4 acc[4] = {{0.f, 0.f, 0.f, 0.f}, {0.f, 0.f, 0.f, 0.f},
                        {0.f, 0.f, 0.f, 0.f}, {0.f, 0.f, 0.f, 0.f}};
#pragma unroll
        for (int t = 0; t < 4; ++t) {
            acc[t] = __builtin_amdgcn_mfma_f32_16x16x32_bf16(a0, wf[t][0], acc[t], 0, 0, 0);
            acc[t] = __builtin_amdgcn_mfma_f32_16x16x32_bf16(a1, wf[t][1], acc[t], 0, 0, 0);
        }
#pragma unroll
        for (int r = 0; r < 4; ++r) {
            int v = base + q * 4 + r;
            if (v < n) {
#pragma unroll
                for (int t = 0; t < 4; ++t) {
                    float val = acc[t][r] + bias[t];
                    val = (val > 0.f) ? val : 0.f;
                    hb_out[(size_t)v * DD + t * 16 + colx] = __float2bfloat16(val);
                }
            }
        }
    }
}

// ---------------------------------------------------------------------------
// Standalone aggregation — fallback tiers.
template<bool PACKED>
__global__ __launch_bounds__(256, 4)
void agg_kernel(const __hip_bfloat16* __restrict__ hb_in,
                const short* __restrict__ eab,
                const int* __restrict__ col, const int* __restrict__ srcv,
                const float* __restrict__ ea,
                const int* __restrict__ rowptr, const int* __restrict__ deg,
                const float* __restrict__ W_edge, const float* __restrict__ b_edge,
                const float* __restrict__ eps, int layer,
                __hip_bfloat16* __restrict__ u, int n) {
    int lane = threadIdx.x & 63;
    int wid = __builtin_amdgcn_readfirstlane(blockIdx.x * 4 + (threadIdx.x >> 6));
    int v0 = wid * 2;
    if (v0 >= n) return;

    float we[7];
#pragma unroll
    for (int k = 0; k < 7; ++k) we[k] = W_edge[k * DD + lane];
    float be = b_edge[lane];
    float epsv = 1.f + eps[layer];

    int beg0 = rowptr[v0];
    int d0   = deg[v0];
    bool has1 = (v0 + 1) < n;
    int beg1 = has1 ? rowptr[v0 + 1] : 0;
    int d1   = has1 ? deg[v0 + 1] : 0;

    float acc0, acc1;
    agg_pair<PACKED>(hb_in, eab, col, ea, srcv, beg0, d0, beg1, d1, has1,
                     lane, we, be, acc0, acc1);

    float self0 = __bfloat162float(hb_in[(size_t)v0 * DD + lane]);
    u[(size_t)v0 * DD + lane] = __float2bfloat16(epsv * self0 + acc0);
    if (has1) {
        float self1 = __bfloat162float(hb_in[(size_t)(v0 + 1) * DD + lane]);
        u[(size_t)(v0 + 1) * DD + lane] = __float2bfloat16(epsv * self1 + acc1);
    }
}

// ---------------------------------------------------------------------------
// Standalone MFMA MLP — fallback tiers.
__global__ __launch_bounds__(256, 4)
void mlp_mfma_kernel(const __hip_bfloat16* __restrict__ u,
                     const __hip_bfloat16* __restrict__ Wt,
                     const float* __restrict__ bmlp,
                     __hip_bfloat16* __restrict__ hb_out, int n) {
    int lane = threadIdx.x & 63;
    int wid  = threadIdx.x >> 6;
    int colx = lane & 15;
    int quad = lane >> 4;
    int v0 = __builtin_amdgcn_readfirstlane((blockIdx.x * 4 + wid) * 16);
    if (v0 >= n) return;

    short8 wf[4][2];
#pragma unroll
    for (int t = 0; t < 4; ++t)
#pragma unroll
        for (int s = 0; s < 2; ++s)
            wf[t][s] = *((const short8*)(Wt + (size_t)(t * 16 + colx) * DD + s * 32 + quad * 8));
    float bias[4];
#pragma unroll
    for (int t = 0; t < 4; ++t) bias[t] = bmlp[t * 16 + colx];

    int vr = v0 + colx;
    int vrc = (vr < n) ? vr : (n - 1);
    const __hip_bfloat16* up = u + (size_t)vrc * DD;
    short8 a0 = *((const short8*)(up + quad * 8));
    short8 a1 = *((const short8*)(up + 32 + quad * 8));

    f32x4 acc[4] = {{0.f, 0.f, 0.f, 0.f}, {0.f, 0.f, 0.f, 0.f},
                    {0.f, 0.f, 0.f, 0.f}, {0.f, 0.f, 0.f, 0.f}};
#pragma unroll
    for (int t = 0; t < 4; ++t) {
        acc[t] = __builtin_amdgcn_mfma_f32_16x16x32_bf16(a0, wf[t][0], acc[t], 0, 0, 0);
        acc[t] = __builtin_amdgcn_mfma_f32_16x16x32_bf16(a1, wf[t][1], acc[t], 0, 0, 0);
    }

#pragma unroll
    for (int r = 0; r < 4; ++r) {
        int v = v0 + quad * 4 + r;
        if (v < n) {
#pragma unroll
            for (int t = 0; t < 4; ++t) {
                float val = acc[t][r] + bias[t];
                val = (val > 0.f) ? val : 0.f;
                hb_out[(size_t)v * DD + t * 16 + colx] = __float2bfloat16(val);
            }
        }
    }
}

// ---------------------------------------------------------------------------
// R25 pool partials: one block per (graph, layer), widened to 512 threads /
// 8 waves — halves the serial per-block row walk (was 68us at 23% occupancy,
// 5.6% VALU, 478 GB/s: pure parallelism starvation, same geometry as
// place R17->R21). Zero atomics preserved.
__global__ void pool_part_kernel(const __hip_bfloat16* __restrict__ htabs, size_t lstride,
                                 const int* __restrict__ batch,
                                 float* __restrict__ g_sum, int n, int G) {
    __shared__ float part[8][DD];
    __shared__ int bnd[2];
    int g = blockIdx.x / NL;
    int q = blockIdx.x % NL;
    int tid = threadIdx.x;
    if (tid < 2) {
        int target = g + tid;
        int lo = 0, hi = n;
        while (lo < hi) { int mid = (lo + hi) >> 1; if (batch[mid] < target) lo = mid + 1; else hi = mid; }
        bnd[tid] = lo;
    }
    __syncthreads();
    int lb = bnd[0], ub = bnd[1];
    int w = tid >> 6, f = tid & 63;
    const __hip_bfloat16* T = htabs + (size_t)q * lstride;
    float s = 0.f;
    for (int v = lb + w; v < ub; v += 8)
        s += __bfloat162float(T[(size_t)v * DD + f]);
    part[w][f] = s;
    __syncthreads();
    if (tid < DD) {
        float tot = part[0][f] + part[1][f] + part[2][f] + part[3][f]
                  + part[4][f] + part[5][f] + part[6][f] + part[7][f];
        float c = (float)(ub - lb);
        if (c < 1.f) c = 1.f;
        g_sum[(size_t)g * LD + q * DD + f] = tot / c;
    }
}

__global__ void readout_mean_kernel(const float* __restrict__ g_mean,
                                    const float* __restrict__ W_pred,
                                    const float* __restrict__ b_pred,
                                    float* __restrict__ out, int G) {
    int id = blockIdx.x * blockDim.x + threadIdx.x;
    if (id >= G * NT) return;
    int g = id / NT, t = id % NT;
    float acc = b_pred[t];
    const float* gs = g_mean + (size_t)g * LD;
    for (int k = 0; k < LD; ++k) acc += gs[k] * W_pred[k * NT + t];
    out[id] = acc;
}

// ---------------------------------------------------------------------------
// Tier-2 fallback pool (run accumulation) + readout
__global__ void pool_kernel(const __hip_bfloat16* __restrict__ h, const int* __restrict__ batch,
                            float* __restrict__ g_sum, int layer, int n) {
    int wave = (blockIdx.x * blockDim.x + threadIdx.x) >> 6;
    int l = threadIdx.x & 63;
    int v0 = wave * 64;
    if (v0 >= n) return;
    int vend = min(v0 + 64, n);
    int cur = batch[v0];
    float acc = 0.f;
    for (int v = v0; v < vend; ++v) {
        int bv = batch[v];
        if (bv != cur) {
            atomicAdd(&g_sum[(size_t)cur * LD + layer * DD + l], acc);
            acc = 0.f;
            cur = bv;
        }
        acc += __bfloat162float(h[(size_t)v * DD + l]);
    }
    atomicAdd(&g_sum[(size_t)cur * LD + layer * DD + l], acc);
}

__global__ void graph_cnt_kernel(const int* __restrict__ batch, int* __restrict__ cnt,
                                 int n, int G) {
    int g = blockIdx.x * blockDim.x + threadIdx.x;
    if (g >= G) return;
    int lo = 0, hi = n;
    while (lo < hi) { int mid = (lo + hi) >> 1; if (batch[mid] < g) lo = mid + 1; else hi = mid; }
    int lb0 = lo;
    lo = lb0; hi = n;
    while (lo < hi) { int mid = (lo + hi) >> 1; if (batch[mid] < g + 1) lo = mid + 1; else hi = mid; }
    cnt[g] = lo - lb0;
}

__global__ void readout_kernel(const float* __restrict__ g_sum, const int* __restrict__ cnt,
                               const float* __restrict__ W_pred, const float* __restrict__ b_pred,
                               float* __restrict__ out, int G) {
    int id = blockIdx.x * blockDim.x + threadIdx.x;
    if (id >= G * NT) return;
    int g = id / NT, t = id % NT;
    float c = (float)cnt[g];
    if (c < 1.f) c = 1.f;
    float inv = 1.f / c;
    float acc = b_pred[t];
    const float* gs = g_sum + (size_t)g * LD;
    for (int k = 0; k < LD; ++k) acc += gs[k] * inv * W_pred[k * NT + t];
    out[id] = acc;
}

// ---------------------------------------------------------------------------
extern "C" void kernel_launch(void* const* d_in, const int* in_sizes, int n_in,
                              void* d_out, int out_size, void* d_ws, size_t ws_size,
                              hipStream_t stream) {
    const float* x       = (const float*)d_in[0];
    const int*   eidx    = (const int*)d_in[1];
    const float* ea      = (const float*)d_in[2];
    const int*   batch   = (const int*)d_in[3];
    const float* W_edge  = (const float*)d_in[4];
    const float* b_edge  = (const float*)d_in[5];
    const float* eps     = (const float*)d_in[6];
    const float* W_mlp   = (const float*)d_in[7];
    const float* b_mlp   = (const float*)d_in[8];
    const float* W_pred  = (const float*)d_in[9];
    const float* b_pred  = (const float*)d_in[10];
    float* out = (float*)d_out;

    const int N = in_sizes[3];          // 100000
    const int E = in_sizes[2] / 7;      // 1250000
    const int G = out_size / NT;        // 128
    const int* src = eidx;              // edge_index[0]
    const int* dst = eidx + E;          // edge_index[1]
    const int NC = (N + 1023) / 1024;
    const int NB = (N + 255) >> 8;      // dst-buckets (256 nodes each)
    const size_t SLOTS = (size_t)E + (size_t)(PB - 1) * N;   // padded-slot capacity

    const size_t S_h = (size_t)N * DD * 2;   // one bf16 table
    const size_t small = (size_t)N * 4 + (size_t)(N + 4) * 4 + (size_t)N * 4 + 4096
                       + 8192 + 4096                          // bucket arrays + webt
                       + (size_t)NL * DD * DD * 2             // Wt
                       + (size_t)G * LD * 4 + (((size_t)G * 4 + 15) & ~(size_t)15);
    const size_t needA = 7 * S_h + small + SLOTS * 20;  // bf16 records + srcv
    const size_t needB = 7 * S_h + small + SLOTS * 8;   // col + srcv
    const int tier = (ws_size >= needA) ? 0 : (ws_size >= needB) ? 1 : 2;
    const int nTab = (tier <= 1) ? 6 : 2;

    char* w = (char*)d_ws;
    __hip_bfloat16* hbt = (__hip_bfloat16*)w;  w += (size_t)nTab * S_h;
    __hip_bfloat16* u   = (__hip_bfloat16*)w;  w += S_h;
    __hip_bfloat16* Wt  = (__hip_bfloat16*)w;  w += (size_t)NL * DD * DD * 2;
    __hip_bfloat16* webt = (__hip_bfloat16*)w; w += 4096;    // [64][32] bf16
    int*   deg    = (int*)w;                   w += (size_t)N * 4;
    int*   rowptr = (int*)w;                   w += (size_t)(N + 4) * 4;
    int*   cursor = (int*)w;                   w += (size_t)N * 4;
    int*   csum   = (int*)w;                   w += 4096;
    int*   bcnt   = (int*)w;                   w += 2048;   // NBMAX ints
    int*   boff   = (int*)w;                   w += 2064;   // NBMAX+1 ints
    int*   bcur   = (int*)w;                   w += 2048;   // NBMAX ints
    float* g_sum  = (float*)w;                 w += (size_t)G * LD * 4;
    int*   cnt    = (int*)w;                   w += ((size_t)G * 4 + 15) & ~(size_t)15;
    short* eab = nullptr; int* col = nullptr; int* srcv = nullptr;
    if (tier == 0) {
        eab  = (short*)w;  w += SLOTS * 16;    // 16-B aligned
        srcv = (int*)w;
    } else {
        col  = (int*)w;    w += SLOTS * 4;
        srcv = (int*)w;
    }
    const bool packed = (tier == 0);

    // Bucketed CSR build requires: buckets fit LDS tables, pair staging fits u.
    const bool newcsr = (NB <= NBMAX) && ((size_t)E * 8 <= S_h);
    i32x2* stage = (i32x2*)u;                  // dead until first agg

    if (tier == 2) hipMemsetAsync(g_sum, 0, (size_t)G * LD * 4, stream);

    // Fused init: bf16 convert + W transpose + webt + bcnt zero (+ legacy deg)
    {
        size_t n1 = (size_t)N * DD;
        size_t tot = n1 + (size_t)(NL * DD * DD) + 2048 + NBMAX + (newcsr ? 0 : (size_t)E);
        if (!newcsr) hipMemsetAsync(deg, 0, (size_t)N * 4, stream);
        init_kernel<<<(unsigned)((tot + 255) / 256), 256, 0, stream>>>(
            x, hbt, n1, W_mlp, Wt, NL * DD * DD, W_edge, b_edge, webt, bcnt,
            dst, deg, E, newcsr ? 0 : 1);
    }

    if (newcsr) {
        unsigned eb4 = (unsigned)((E + 4095) / 4096);
        bhist_kernel<<<eb4, 256, 0, stream>>>(dst, bcnt, E);
        bscan_kernel<<<1, 256, 0, stream>>>(bcnt, boff, bcur);
        pscat_kernel<<<eb4, 256, 0, stream>>>(dst, bcur, stage, E);
        bdeg_kernel<<<NB, 256, 0, stream>>>(stage, boff, deg, N);
        chunksum_kernel<<<NC, 256, 0, stream>>>(deg, csum, N);
        scansums_kernel<<<1, 256, 0, stream>>>(csum, NC, rowptr + N);
        chunkscan_kernel<<<NC, 256, 0, stream>>>(deg, csum, rowptr, cursor, N);
        if (packed)
            place_kernel<true><<<NB, 512, 0, stream>>>(stage, boff, rowptr, src, ea,
                                                       eab, srcv, col, N);
        else
            place_kernel<false><<<NB, 512, 0, stream>>>(stage, boff, rowptr, src, ea,
                                                        eab, srcv, col, N);
    } else {
        chunksum_kernel<<<NC, 256, 0, stream>>>(deg, csum, N);
        scansums_kernel<<<1, 256, 0, stream>>>(csum, NC, rowptr + N);
        chunkscan_kernel<<<NC, 256, 0, stream>>>(deg, csum, rowptr, cursor, N);
        int* colbuf = nullptr;
        if (tier == 0) {
            if (SLOTS * 4 <= S_h) colbuf = (int*)u;
        } else {
            colbuf = col;
        }
        if (colbuf) {
            fillpos_kernel<<<(E + 255) / 256, 256, 0, stream>>>(dst, cursor, colbuf, E);
            padmark_kernel<<<(N + 255) / 256, 256, 0, stream>>>(deg, rowptr, colbuf, N);
            unsigned gblocks = (unsigned)((SLOTS + 255) / 256);
            if (packed)
                gfill_kernel<true><<<gblocks, 256, 0, stream>>>(colbuf, src, ea, rowptr + N,
                                                                eab, srcv, colbuf);
            else
                gfill_kernel<false><<<gblocks, 256, 0, stream>>>(colbuf, src, ea, rowptr + N,
                                                                 eab, srcv, colbuf);
        } else {
            if (packed)
                fill_kernel<true><<<(E + 255) / 256, 256, 0, stream>>>(dst, src, ea, cursor,
                                                                       eab, col, srcv, E);
            else
                fill_kernel<false><<<(E + 255) / 256, 256, 0, stream>>>(dst, src, ea, cursor,
                                                                        eab, col, srcv, E);
            padfill_kernel<<<(N + 255) / 256, 256, 0, stream>>>(deg, rowptr, srcv,
                                                                col ? col : srcv,
                                                                col ? 1 : 0, N);
        }
    }

    const bool useFused = newcsr && packed;
    int fusedBlocks = (N + 15) / 16;
    int aggBlocks = (N + 7) / 8;
    int mlpBlocks = (N + 63) / 64;
    for (int i = 0; i < NL; ++i) {
        __hip_bfloat16* hin  = (tier <= 1) ? (hbt + (size_t)i * N * DD)
                                           : (hbt + (size_t)(i & 1) * N * DD);
        __hip_bfloat16* hout = (tier <= 1) ? (hbt + (size_t)(i + 1) * N * DD)
                                           : (hbt + (size_t)((i + 1) & 1) * N * DD);
        if (useFused) {
            aggmlp_kernel<<<fusedBlocks, 256, 0, stream>>>(
                hin, eab, srcv, rowptr, deg, W_edge, b_edge, webt, eps, i,
                Wt + (size_t)i * DD * DD, b_mlp + (size_t)i * DD, hout, N);
        } else {
            if (packed)
                agg_kernel<true><<<aggBlocks, 256, 0, stream>>>(
                    hin, eab, col, srcv, ea, rowptr, deg, W_edge, b_edge, eps, i, u, N);
            else
                agg_kernel<false><<<aggBlocks, 256, 0, stream>>>(
                    hin, eab, col, srcv, ea, rowptr, deg, W_edge, b_edge, eps, i, u, N);
            mlp_mfma_kernel<<<mlpBlocks, 256, 0, stream>>>(
                u, Wt + (size_t)i * DD * DD, b_mlp + (size_t)i * DD, hout, N);
        }
        if (tier == 2)
            pool_kernel<<<((N + 63) / 64 * 64 + 255) / 256, 256, 0, stream>>>(hout, batch,
                                                                              g_sum, i, N);
    }

    if (tier <= 1) {
        pool_part_kernel<<<G * NL, 512, 0, stream>>>(hbt + (size_t)N * DD, (size_t)N * DD,
                                                     batch, g_sum, N, G);
        readout_mean_kernel<<<(G * NT + 255) / 256, 256, 0, stream>>>(g_sum, W_pred, b_pred,
                                                                      out, G);
    } else {
        graph_cnt_kernel<<<1, 128, 0, stream>>>(batch, cnt, N, G);
        readout_kernel<<<(G * NT + 255) / 256, 256, 0, stream>>>(g_sum, cnt, W_pred, b_pred,
                                                                 out, G);
    }
}